// Round 13
// baseline (1222.251 us; speedup 1.0000x reference)
//
#include <hip/hip_runtime.h>
#include <hip/hip_bf16.h>

// Sizes
#define B_ 256
#define D_ 3072
#define H_ 256
#define OPT_ 32
#define OD_ 98304       // OPT_*D_
#define NL_ 4

typedef __attribute__((ext_vector_type(8))) short short8;
typedef __attribute__((ext_vector_type(4))) float f32x4;

__device__ __forceinline__ unsigned short f2bf(float f) {
    unsigned int u = __float_as_uint(f);
    unsigned int r = (u + 0x7FFFu + ((u >> 16) & 1u)) >> 16;
    return (unsigned short)r;
}

// ---------------------------------------------------------------------------
// E: base = relu(z + bb) -> bf16 image + f32 basef.  Also resets the d-flag
// for this layer (runs strictly before d in stream order -> poison-proof).
__global__ __launch_bounds__(256) void e_kernel(const float* __restrict__ zpart2,
                                                const float* __restrict__ bb,
                                                unsigned char* __restrict__ base_ready,
                                                float* __restrict__ basef,
                                                int* __restrict__ dflag,
                                                int first) {
    if (blockIdx.x == 0 && threadIdx.x == 0)
        __hip_atomic_store(dflag, 0, __ATOMIC_RELAXED, __HIP_MEMORY_SCOPE_AGENT);
    int m = blockIdx.x, k = threadIdx.x;
    float z = bb[k];
    if (!first) {
#pragma unroll
        for (int dt = 0; dt < 12; ++dt) z += zpart2[dt * (B_ * H_) + m * H_ + k];
    }
    z = z > 0.f ? z : 0.f;
    *(unsigned short*)(base_ready + (k >> 5) * 20480 + m * 80 + (k & 31) * 2) = f2bf(z);
    basef[m * H_ + k] = z;
}

// ---------------------------------------------------------------------------
// G2 (R7 schedule verbatim): fused GEMM (256x98304, K=256, bf16 MFMA) +
// squared-loss partials. rp/rsign: layer 0 reads x with rsign=-1.
__global__ __launch_bounds__(512, 4) void g2_kernel(const unsigned char* __restrict__ base_ready,
                                                    const float* __restrict__ Wo,    // [256][98304] layer slice
                                                    const float* __restrict__ biasL, // [32*3072]
                                                    const float* __restrict__ boL,   // [98304]
                                                    const float* __restrict__ rp,    // rx or x
                                                    float rsign,
                                                    float* __restrict__ partial) {
    __shared__ __align__(16) unsigned char ldsA[2][20480];  // [m][32k bf16 + pad]
    __shared__ __align__(16) unsigned char ldsW[2][10240];  // [n][32k bf16 + pad]

    int t = threadIdx.x;
    int lane = t & 63, wv = t >> 6;
    int bx = blockIdx.x;
    int ncol0 = bx * 128;
    int o = bx / 24;                 // 24 blocks per option
    int dbase = (bx % 24) * 128;

    int wm = wv >> 1, wn = wv & 1;
    int lrow = lane & 15, lk = lane >> 4;
    int nW = t & 127, kq = t >> 7;   // W staging role: kq in 0..3

    f32x4 acc[4][4];
#pragma unroll
    for (int mi = 0; mi < 4; ++mi)
#pragma unroll
        for (int ni = 0; ni < 4; ++ni) acc[mi][ni] = 0.f;

    float wfX[8], wfY[8];

#define DMA_A(S, BUF) {                                                                  \
    const unsigned char* gA = base_ready + (S) * 20480;                                  \
    __builtin_amdgcn_global_load_lds(                                                    \
        (const __attribute__((address_space(1))) unsigned int*)(gA + t * 16),            \
        (__attribute__((address_space(3))) unsigned int*)(&ldsA[BUF][0] + wv * 1024),    \
        16, 0, 0);                                                                       \
    __builtin_amdgcn_global_load_lds(                                                    \
        (const __attribute__((address_space(1))) unsigned int*)(gA + 8192 + t * 16),     \
        (__attribute__((address_space(3))) unsigned int*)(&ldsA[BUF][0] + 8192 + wv * 1024), \
        16, 0, 0);                                                                       \
    if (wv < 4)                                                                          \
        __builtin_amdgcn_global_load_lds(                                                \
            (const __attribute__((address_space(1))) unsigned int*)(gA + 16384 + t * 16),\
            (__attribute__((address_space(3))) unsigned int*)(&ldsA[BUF][0] + 16384 + wv * 1024), \
            16, 0, 0); }

#define LOADW_(S, WF) {                                                                  \
    const float* gp0 = Wo + (size_t)((S) * 32 + kq * 4) * OD_ + ncol0 + nW;              \
    WF[0] = gp0[0]; WF[1] = gp0[OD_]; WF[2] = gp0[2 * OD_]; WF[3] = gp0[3 * OD_];        \
    const float* gp1 = gp0 + (size_t)16 * OD_;                                           \
    WF[4] = gp1[0]; WF[5] = gp1[OD_]; WF[6] = gp1[2 * OD_]; WF[7] = gp1[3 * OD_]; }

#define WRITEW_(BUF, WF) {                                                               \
    uint2 pk0, pk1;                                                                      \
    pk0.x = (unsigned)f2bf(WF[0]) | ((unsigned)f2bf(WF[1]) << 16);                       \
    pk0.y = (unsigned)f2bf(WF[2]) | ((unsigned)f2bf(WF[3]) << 16);                       \
    *(uint2*)(ldsW[BUF] + nW * 80 + kq * 8) = pk0;                                       \
    pk1.x = (unsigned)f2bf(WF[4]) | ((unsigned)f2bf(WF[5]) << 16);                       \
    pk1.y = (unsigned)f2bf(WF[6]) | ((unsigned)f2bf(WF[7]) << 16);                       \
    *(uint2*)(ldsW[BUF] + nW * 80 + 32 + kq * 8) = pk1; }

    DMA_A(0, 0);
    LOADW_(0, wfX);
    LOADW_(1, wfY);
    WRITEW_(0, wfX);
    asm volatile("s_waitcnt lgkmcnt(0)" ::: "memory");
    __builtin_amdgcn_s_barrier();

#pragma unroll 2
    for (int s = 0; s < 8; ++s) {
        int cur = s & 1;
        if (s < 7) DMA_A(s + 1, cur ^ 1);
        if (s < 6) {
            if ((s & 1) == 0) { LOADW_(s + 2, wfX); }
            else              { LOADW_(s + 2, wfY); }
        }
        short8 bfr[4];
#pragma unroll
        for (int ni = 0; ni < 4; ++ni) {
            int nn = wn * 64 + ni * 16 + lrow;
            bfr[ni] = *(const short8*)(ldsW[cur] + nn * 80 + lk * 16);
        }
#pragma unroll
        for (int mi = 0; mi < 4; ++mi) {
            int row = wm * 64 + mi * 16 + lrow;
            short8 af = *(const short8*)(ldsA[cur] + row * 80 + lk * 16);
#pragma unroll
            for (int ni = 0; ni < 4; ++ni)
                acc[mi][ni] = __builtin_amdgcn_mfma_f32_16x16x32_bf16(af, bfr[ni], acc[mi][ni], 0, 0, 0);
        }
        if (s < 7) {
            if ((s & 1) == 0) { WRITEW_(cur ^ 1, wfY); }
            else              { WRITEW_(cur ^ 1, wfX); }
            if (s < 6) asm volatile("s_waitcnt vmcnt(8) lgkmcnt(0)" ::: "memory");  // drain A(s+1); keep W(s+2)
            else       asm volatile("s_waitcnt vmcnt(0) lgkmcnt(0)" ::: "memory");  // last: drain A(7)
            __builtin_amdgcn_s_barrier();
        }
    }

#undef DMA_A
#undef LOADW_
#undef WRITEW_

    // epilogue: loss partials
    float q[4];
#pragma unroll
    for (int ni = 0; ni < 4; ++ni) {
        int dcol = dbase + wn * 64 + ni * 16 + lrow;
        q[ni] = biasL[o * D_ + dcol] + boL[o * D_ + dcol];
    }
    float ssum[4][4];
#pragma unroll
    for (int mi = 0; mi < 4; ++mi)
#pragma unroll
        for (int r = 0; r < 4; ++r) ssum[mi][r] = 0.f;

#pragma unroll
    for (int mi = 0; mi < 4; ++mi) {
#pragma unroll
        for (int ni = 0; ni < 4; ++ni) {
            int dcol = dbase + wn * 64 + ni * 16 + lrow;
#pragma unroll
            for (int r = 0; r < 4; ++r) {
                int rowm = wm * 64 + mi * 16 + lk * 4 + r;
                float tv = acc[mi][ni][r] + rsign * rp[rowm * D_ + dcol] + q[ni];
                ssum[mi][r] += tv * tv;
            }
        }
    }
#pragma unroll
    for (int mi = 0; mi < 4; ++mi)
#pragma unroll
        for (int r = 0; r < 4; ++r) {
            float v = ssum[mi][r];
            v += __shfl_xor(v, 1);
            v += __shfl_xor(v, 2);
            v += __shfl_xor(v, 4);
            v += __shfl_xor(v, 8);
            if (lrow == 0) {
                int rowm = wm * 64 + mi * 16 + lk * 4 + r;
                partial[(rowm * OPT_ + o) * 48 + (bx % 24) * 2 + wn] = v;
            }
        }
}

// ---------------------------------------------------------------------------
// D: argmin (fused c) + bucketed recompute + fused next-layer gemm1 tail.
// Block (0,0) computes idxbuf for all 256 b -- bitwise-identical to the old
// c_kernel: s[j8] = serial j-ascending sums, tree ((s0+s1)+(s2+s3))+((s4+s5)
// +(s6+s7)), strict-< lowest-index tie-break -- then publishes via
// threadfence + device-scope release flag. Other 383 blocks acquire-spin
// (384 blocks << co-resident capacity -> no deadlock regardless of dispatch
// order; e_kernel reset the flag earlier in stream order).
__global__ __launch_bounds__(256) void d_kernel(const float* __restrict__ partial,
                                                float* __restrict__ enc, int layer,
                                                int* __restrict__ idxbuf,
                                                int* __restrict__ dflag,
                                                const float* __restrict__ basef,
                                                const float* __restrict__ Wo,
                                                const float* __restrict__ boL,
                                                const float* __restrict__ biasL,
                                                const float* __restrict__ x,
                                                const float* __restrict__ Wb,
                                                float* __restrict__ cur,
                                                float* __restrict__ rx,
                                                float* __restrict__ zpart2,
                                                int first, int last) {
    __shared__ int sidx[256];
    __shared__ int scnt[32];
    __shared__ int snch[32];
    __shared__ int chunk_b[8];
    __shared__ float basL[8][256];
    int t = threadIdx.x;
    int dt = blockIdx.y;

    if (blockIdx.x == 0 && blockIdx.y == 0) {
        // fused c: thread t = example b
        const float* pp0 = partial + (size_t)t * OPT_ * 48;
        float best = 0.f;
        int bi = 0;
        for (int o = 0; o < 32; ++o) {
            const float* pp = pp0 + o * 48;
            float s[8];
#pragma unroll
            for (int j8 = 0; j8 < 8; ++j8) {
                float sv = pp[j8];
#pragma unroll
                for (int j = 1; j < 6; ++j) sv += pp[j8 + 8 * j];
                s[j8] = sv;
            }
            float v = ((s[0] + s[1]) + (s[2] + s[3])) + ((s[4] + s[5]) + (s[6] + s[7]));
            if (o == 0 || v < best) { best = v; bi = o; }
        }
        idxbuf[t] = bi;
        enc[t * NL_ + layer] = (float)bi;
        sidx[t] = bi;
        __syncthreads();
        __threadfence();
        if (t == 0)
            __hip_atomic_store(dflag, 1, __ATOMIC_RELEASE, __HIP_MEMORY_SCOPE_AGENT);
    } else {
        if (t == 0) {
            while (__hip_atomic_load(dflag, __ATOMIC_ACQUIRE, __HIP_MEMORY_SCOPE_AGENT) != 1)
                __builtin_amdgcn_s_sleep(8);
        }
        __syncthreads();    // t0's acquire orders the block
        sidx[t] = idxbuf[t];
        __syncthreads();
    }

    if (t < 32) {
        int c = 0;
        for (int b = 0; b < 256; ++b) c += (sidx[b] == t);
        scnt[t] = c;
        snch[t] = (c + 7) >> 3;
    }
    __syncthreads();
    int myo = sidx[t];
    int myrank = 0;
    for (int b = 0; b < t; ++b) myrank += (sidx[b] == myo);

    for (int j = blockIdx.x; ; j += 32) {
        int o = -1, ch = 0, pre = 0;
        for (int oo = 0; oo < 32; ++oo) {
            int n = snch[oo];
            if (j < pre + n) { o = oo; ch = j - pre; break; }
            pre += n;
        }
        if (o < 0) break;
        int cnt = scnt[o];
        int c0 = ch * 8;
        int rem = cnt - c0;
        if (rem > 8) rem = 8;

        __syncthreads();   // previous item's basL readers done before reuse
        if (myo == o && myrank >= c0 && myrank < c0 + 8) chunk_b[myrank - c0] = t;
        __syncthreads();

        int bidx[8];
#pragma unroll
        for (int g = 0; g < 8; ++g) bidx[g] = chunk_b[(g < rem) ? g : (rem - 1)];
#pragma unroll
        for (int g = 0; g < 8; ++g) basL[g][t] = basef[bidx[g] * H_ + t];
        __syncthreads();

        int d = dt * 256 + t;
        const float* wp = Wo + (size_t)o * D_ + d;
        size_t nn = (size_t)o * D_ + d;
        float bov = boL[nn];
        float biv = biasL[nn];

        float acc[8] = {0.f, 0.f, 0.f, 0.f, 0.f, 0.f, 0.f, 0.f};
        for (int k0 = 0; k0 < 256; k0 += 8) {
            float w[8];
#pragma unroll
            for (int u = 0; u < 8; ++u) w[u] = wp[(size_t)(k0 + u) * OD_];
#pragma unroll
            for (int h = 0; h < 2; ++h) {
                int kb = k0 + h * 4;
                f32x4 bv[8];
#pragma unroll
                for (int g = 0; g < 8; ++g) bv[g] = *(const f32x4*)&basL[g][kb];
#pragma unroll
                for (int u = 0; u < 4; ++u) {
                    float wu = w[h * 4 + u];
#pragma unroll
                    for (int g = 0; g < 8; ++g) acc[g] += bv[g][u] * wu;   // k ascending
                }
            }
        }
        float fout[8] = {0.f, 0.f, 0.f, 0.f, 0.f, 0.f, 0.f, 0.f};
#pragma unroll
        for (int g = 0; g < 8; ++g) {
            if (g < rem) {
                int b = bidx[g];
                float cv = first ? 0.f : cur[b * D_ + d];
                float outv = cv + acc[g] + bov + biv;
                fout[g] = outv;
                cur[b * D_ + d] = outv;
                rx[b * D_ + d] = outv - x[b * D_ + d];
            }
        }

        // ---- fused gemm1 tail: zpart2[dt][b][h] for next layer's base ----
        if (!last) {
            __syncthreads();                 // k-loop readers of basL done
#pragma unroll
            for (int g = 0; g < 8; ++g) basL[g][t] = fout[g];   // now holds cur slice
            __syncthreads();
            const float* wbp = Wb + (size_t)(dt * 256) * H_ + t;
            float zacc[8] = {0.f, 0.f, 0.f, 0.f, 0.f, 0.f, 0.f, 0.f};
#pragma unroll 4
            for (int dd = 0; dd < 256; ++dd) {
                float w = wbp[(size_t)dd * H_];
#pragma unroll
                for (int g = 0; g < 8; ++g) zacc[g] += basL[g][dd] * w;   // d ascending
            }
#pragma unroll
            for (int g = 0; g < 8; ++g)
                if (g < rem)
                    zpart2[dt * (B_ * H_) + bidx[g] * H_ + t] = zacc[g];
        }
    }
}

// ---------------------------------------------------------------------------
extern "C" void kernel_launch(void* const* d_in, const int* in_sizes, int n_in,
                              void* d_out, int out_size, void* d_ws, size_t ws_size,
                              hipStream_t stream) {
    const float* x    = (const float*)d_in[0];  // [256][3072]
    const float* Wb   = (const float*)d_in[1];  // [3072][256]
    const float* bb   = (const float*)d_in[2];  // [256]
    const float* Wo   = (const float*)d_in[3];  // [4][256][98304]
    const float* bo   = (const float*)d_in[4];  // [4][98304]
    const float* bias = (const float*)d_in[5];  // [4][32][3072]

    float* out = (float*)d_out;
    float* enc = out;            // [256][4] (indices as float)
    float* cur = out + 1024;     // [256][3072] reconstruction

    float* ws = (float*)d_ws;
    float* zpart2  = ws;                          // 12*256*256 = 786432
    float* partial = ws + 786432;                 // 256*32*48  = 393216
    float* rx      = ws + 1179648;                // 256*3072   = 786432
    float* basef   = ws + 1966080;                // 256*256    = 65536
    unsigned char* base_ready = (unsigned char*)(ws + 2031616);  // 163840 B
    int* idxbuf    = (int*)(ws + 2072576);        // 256 ints
    int* dflag     = (int*)(ws + 2072832);        // 1 int

    for (int i = 0; i < NL_; ++i) {
        const float* WoL   = Wo + (size_t)i * H_ * OD_;
        const float* boLp  = bo + (size_t)i * OD_;
        const float* biasL = bias + (size_t)i * OD_;
        const float* rp    = (i == 0) ? x : rx;
        float rsign        = (i == 0) ? -1.f : 1.f;
        e_kernel<<<256, 256, 0, stream>>>(zpart2, bb, base_ready, basef, dflag, i == 0);
        g2_kernel<<<768, 512, 0, stream>>>(base_ready, WoL, biasL, boLp, rp, rsign, partial);
        d_kernel<<<dim3(32, 12), 256, 0, stream>>>(partial, enc, i, idxbuf, dflag,
                                                   basef, WoL, boLp, biasL, x, Wb,
                                                   cur, rx, zpart2, i == 0, i == NL_ - 1);
    }
}

// Round 14
// 469.315 us; speedup vs baseline: 2.6043x; 2.6043x over previous
//
#include <hip/hip_runtime.h>
#include <hip/hip_bf16.h>

// Sizes
#define B_ 256
#define D_ 3072
#define H_ 256
#define OPT_ 32
#define OD_ 98304       // OPT_*D_
#define NL_ 4

typedef __attribute__((ext_vector_type(8))) short short8;
typedef __attribute__((ext_vector_type(4))) float f32x4;

__device__ __forceinline__ unsigned short f2bf(float f) {
    unsigned int u = __float_as_uint(f);
    unsigned int r = (u + 0x7FFFu + ((u >> 16) & 1u)) >> 16;
    return (unsigned short)r;
}

// ---------------------------------------------------------------------------
// E: base = relu(z + bb) -> bf16 image + f32 basef.  Resets the d argmin
// counter (runs strictly before d in stream order -> poison-proof).
__global__ __launch_bounds__(256) void e_kernel(const float* __restrict__ zpart2,
                                                const float* __restrict__ bb,
                                                unsigned char* __restrict__ base_ready,
                                                float* __restrict__ basef,
                                                int* __restrict__ dcnt,
                                                int first) {
    if (blockIdx.x == 0 && threadIdx.x == 0)
        __hip_atomic_store(dcnt, 0, __ATOMIC_RELAXED, __HIP_MEMORY_SCOPE_AGENT);
    int m = blockIdx.x, k = threadIdx.x;
    float z = bb[k];
    if (!first) {
#pragma unroll
        for (int dt = 0; dt < 12; ++dt) z += zpart2[dt * (B_ * H_) + m * H_ + k];
    }
    z = z > 0.f ? z : 0.f;
    *(unsigned short*)(base_ready + (k >> 5) * 20480 + m * 80 + (k & 31) * 2) = f2bf(z);
    basef[m * H_ + k] = z;
}

// ---------------------------------------------------------------------------
// G2 (R7 schedule verbatim): fused GEMM (256x98304, K=256, bf16 MFMA) +
// squared-loss partials. rp/rsign: layer 0 reads x with rsign=-1.
__global__ __launch_bounds__(512, 4) void g2_kernel(const unsigned char* __restrict__ base_ready,
                                                    const float* __restrict__ Wo,    // [256][98304] layer slice
                                                    const float* __restrict__ biasL, // [32*3072]
                                                    const float* __restrict__ boL,   // [98304]
                                                    const float* __restrict__ rp,    // rx or x
                                                    float rsign,
                                                    float* __restrict__ partial) {
    __shared__ __align__(16) unsigned char ldsA[2][20480];  // [m][32k bf16 + pad]
    __shared__ __align__(16) unsigned char ldsW[2][10240];  // [n][32k bf16 + pad]

    int t = threadIdx.x;
    int lane = t & 63, wv = t >> 6;
    int bx = blockIdx.x;
    int ncol0 = bx * 128;
    int o = bx / 24;                 // 24 blocks per option
    int dbase = (bx % 24) * 128;

    int wm = wv >> 1, wn = wv & 1;
    int lrow = lane & 15, lk = lane >> 4;
    int nW = t & 127, kq = t >> 7;   // W staging role: kq in 0..3

    f32x4 acc[4][4];
#pragma unroll
    for (int mi = 0; mi < 4; ++mi)
#pragma unroll
        for (int ni = 0; ni < 4; ++ni) acc[mi][ni] = 0.f;

    float wfX[8], wfY[8];

#define DMA_A(S, BUF) {                                                                  \
    const unsigned char* gA = base_ready + (S) * 20480;                                  \
    __builtin_amdgcn_global_load_lds(                                                    \
        (const __attribute__((address_space(1))) unsigned int*)(gA + t * 16),            \
        (__attribute__((address_space(3))) unsigned int*)(&ldsA[BUF][0] + wv * 1024),    \
        16, 0, 0);                                                                       \
    __builtin_amdgcn_global_load_lds(                                                    \
        (const __attribute__((address_space(1))) unsigned int*)(gA + 8192 + t * 16),     \
        (__attribute__((address_space(3))) unsigned int*)(&ldsA[BUF][0] + 8192 + wv * 1024), \
        16, 0, 0);                                                                       \
    if (wv < 4)                                                                          \
        __builtin_amdgcn_global_load_lds(                                                \
            (const __attribute__((address_space(1))) unsigned int*)(gA + 16384 + t * 16),\
            (__attribute__((address_space(3))) unsigned int*)(&ldsA[BUF][0] + 16384 + wv * 1024), \
            16, 0, 0); }

#define LOADW_(S, WF) {                                                                  \
    const float* gp0 = Wo + (size_t)((S) * 32 + kq * 4) * OD_ + ncol0 + nW;              \
    WF[0] = gp0[0]; WF[1] = gp0[OD_]; WF[2] = gp0[2 * OD_]; WF[3] = gp0[3 * OD_];        \
    const float* gp1 = gp0 + (size_t)16 * OD_;                                           \
    WF[4] = gp1[0]; WF[5] = gp1[OD_]; WF[6] = gp1[2 * OD_]; WF[7] = gp1[3 * OD_]; }

#define WRITEW_(BUF, WF) {                                                               \
    uint2 pk0, pk1;                                                                      \
    pk0.x = (unsigned)f2bf(WF[0]) | ((unsigned)f2bf(WF[1]) << 16);                       \
    pk0.y = (unsigned)f2bf(WF[2]) | ((unsigned)f2bf(WF[3]) << 16);                       \
    *(uint2*)(ldsW[BUF] + nW * 80 + kq * 8) = pk0;                                       \
    pk1.x = (unsigned)f2bf(WF[4]) | ((unsigned)f2bf(WF[5]) << 16);                       \
    pk1.y = (unsigned)f2bf(WF[6]) | ((unsigned)f2bf(WF[7]) << 16);                       \
    *(uint2*)(ldsW[BUF] + nW * 80 + 32 + kq * 8) = pk1; }

    DMA_A(0, 0);
    LOADW_(0, wfX);
    LOADW_(1, wfY);
    WRITEW_(0, wfX);
    asm volatile("s_waitcnt lgkmcnt(0)" ::: "memory");
    __builtin_amdgcn_s_barrier();

#pragma unroll 2
    for (int s = 0; s < 8; ++s) {
        int cur = s & 1;
        if (s < 7) DMA_A(s + 1, cur ^ 1);
        if (s < 6) {
            if ((s & 1) == 0) { LOADW_(s + 2, wfX); }
            else              { LOADW_(s + 2, wfY); }
        }
        short8 bfr[4];
#pragma unroll
        for (int ni = 0; ni < 4; ++ni) {
            int nn = wn * 64 + ni * 16 + lrow;
            bfr[ni] = *(const short8*)(ldsW[cur] + nn * 80 + lk * 16);
        }
#pragma unroll
        for (int mi = 0; mi < 4; ++mi) {
            int row = wm * 64 + mi * 16 + lrow;
            short8 af = *(const short8*)(ldsA[cur] + row * 80 + lk * 16);
#pragma unroll
            for (int ni = 0; ni < 4; ++ni)
                acc[mi][ni] = __builtin_amdgcn_mfma_f32_16x16x32_bf16(af, bfr[ni], acc[mi][ni], 0, 0, 0);
        }
        if (s < 7) {
            if ((s & 1) == 0) { WRITEW_(cur ^ 1, wfY); }
            else              { WRITEW_(cur ^ 1, wfX); }
            if (s < 6) asm volatile("s_waitcnt vmcnt(8) lgkmcnt(0)" ::: "memory");  // drain A(s+1); keep W(s+2)
            else       asm volatile("s_waitcnt vmcnt(0) lgkmcnt(0)" ::: "memory");  // last: drain A(7)
            __builtin_amdgcn_s_barrier();
        }
    }

#undef DMA_A
#undef LOADW_
#undef WRITEW_

    // epilogue: loss partials
    float q[4];
#pragma unroll
    for (int ni = 0; ni < 4; ++ni) {
        int dcol = dbase + wn * 64 + ni * 16 + lrow;
        q[ni] = biasL[o * D_ + dcol] + boL[o * D_ + dcol];
    }
    float ssum[4][4];
#pragma unroll
    for (int mi = 0; mi < 4; ++mi)
#pragma unroll
        for (int r = 0; r < 4; ++r) ssum[mi][r] = 0.f;

#pragma unroll
    for (int mi = 0; mi < 4; ++mi) {
#pragma unroll
        for (int ni = 0; ni < 4; ++ni) {
            int dcol = dbase + wn * 64 + ni * 16 + lrow;
#pragma unroll
            for (int r = 0; r < 4; ++r) {
                int rowm = wm * 64 + mi * 16 + lk * 4 + r;
                float tv = acc[mi][ni][r] + rsign * rp[rowm * D_ + dcol] + q[ni];
                ssum[mi][r] += tv * tv;
            }
        }
    }
#pragma unroll
    for (int mi = 0; mi < 4; ++mi)
#pragma unroll
        for (int r = 0; r < 4; ++r) {
            float v = ssum[mi][r];
            v += __shfl_xor(v, 1);
            v += __shfl_xor(v, 2);
            v += __shfl_xor(v, 4);
            v += __shfl_xor(v, 8);
            if (lrow == 0) {
                int rowm = wm * 64 + mi * 16 + lk * 4 + r;
                partial[(rowm * OPT_ + o) * 48 + (bx % 24) * 2 + wn] = v;
            }
        }
}

// ---------------------------------------------------------------------------
// D: argmin (fused c, DISTRIBUTED) + bucketed recompute + fused gemm1 tail.
// Blocks bid = y*32+x < 256 each run the old c_kernel body VERBATIM for
// b = bid (cooperative coalesced layout -- R13's single-block version gave
// each thread a private 6KB strip = 64-way address divergence, ~250us).
// Publish via threadfence + release atomicAdd(dcnt); all 384 blocks
// acquire-spin until dcnt >= 256 (idempotent under replay; e resets dcnt
// in stream order). 384 blocks << co-resident capacity -> no deadlock.
__global__ __launch_bounds__(256) void d_kernel(const float* __restrict__ partial,
                                                float* __restrict__ enc, int layer,
                                                int* __restrict__ idxbuf,
                                                int* __restrict__ dcnt,
                                                const float* __restrict__ basef,
                                                const float* __restrict__ Wo,
                                                const float* __restrict__ boL,
                                                const float* __restrict__ biasL,
                                                const float* __restrict__ x,
                                                const float* __restrict__ Wb,
                                                float* __restrict__ cur,
                                                float* __restrict__ rx,
                                                float* __restrict__ zpart2,
                                                int first, int last) {
    __shared__ float ls[32];
    __shared__ int sidx[256];
    __shared__ int scnt[32];
    __shared__ int snch[32];
    __shared__ int chunk_b[8];
    __shared__ float basL[8][256];
    int t = threadIdx.x;
    int dt = blockIdx.y;
    int bid = blockIdx.y * 32 + blockIdx.x;   // 0..383

    if (bid < 256) {
        // old c_kernel body verbatim, b = bid
        int oo = t >> 3, j8 = t & 7;
        const float* pp = partial + (bid * OPT_ + oo) * 48;
        float v = 0.f;
#pragma unroll
        for (int j = 0; j < 6; ++j) v += pp[j8 + 8 * j];
        v += __shfl_xor(v, 1);
        v += __shfl_xor(v, 2);
        v += __shfl_xor(v, 4);
        if (j8 == 0) ls[oo] = v;
        __syncthreads();
        if (t < 32) {
            float mv = ls[t];
            int mi = t;
#pragma unroll
            for (int m = 16; m >= 1; m >>= 1) {
                float ov = __shfl_xor(mv, m);
                int oi = __shfl_xor(mi, m);
                if (ov < mv || (ov == mv && oi < mi)) { mv = ov; mi = oi; }
            }
            if (t == 0) {
                idxbuf[bid] = mi;
                enc[bid * NL_ + layer] = (float)mi;
            }
        }
        __syncthreads();
        if (t == 0) {
            __threadfence();
            __hip_atomic_fetch_add(dcnt, 1, __ATOMIC_RELEASE, __HIP_MEMORY_SCOPE_AGENT);
        }
    }
    // all blocks wait for the full idxbuf
    if (t == 0) {
        while (__hip_atomic_load(dcnt, __ATOMIC_ACQUIRE, __HIP_MEMORY_SCOPE_AGENT) < 256)
            __builtin_amdgcn_s_sleep(2);
    }
    __syncthreads();    // t0's acquire orders the block
    sidx[t] = idxbuf[t];
    __syncthreads();

    if (t < 32) {
        int c = 0;
        for (int b = 0; b < 256; ++b) c += (sidx[b] == t);
        scnt[t] = c;
        snch[t] = (c + 7) >> 3;
    }
    __syncthreads();
    int myo = sidx[t];
    int myrank = 0;
    for (int b = 0; b < t; ++b) myrank += (sidx[b] == myo);

    for (int j = blockIdx.x; ; j += 32) {
        int o = -1, ch = 0, pre = 0;
        for (int oo = 0; oo < 32; ++oo) {
            int n = snch[oo];
            if (j < pre + n) { o = oo; ch = j - pre; break; }
            pre += n;
        }
        if (o < 0) break;
        int cnt = scnt[o];
        int c0 = ch * 8;
        int rem = cnt - c0;
        if (rem > 8) rem = 8;

        __syncthreads();   // previous item's basL readers done before reuse
        if (myo == o && myrank >= c0 && myrank < c0 + 8) chunk_b[myrank - c0] = t;
        __syncthreads();

        int bidx[8];
#pragma unroll
        for (int g = 0; g < 8; ++g) bidx[g] = chunk_b[(g < rem) ? g : (rem - 1)];
#pragma unroll
        for (int g = 0; g < 8; ++g) basL[g][t] = basef[bidx[g] * H_ + t];
        __syncthreads();

        int d = dt * 256 + t;
        const float* wp = Wo + (size_t)o * D_ + d;
        size_t nn = (size_t)o * D_ + d;
        float bov = boL[nn];
        float biv = biasL[nn];

        float acc[8] = {0.f, 0.f, 0.f, 0.f, 0.f, 0.f, 0.f, 0.f};
        for (int k0 = 0; k0 < 256; k0 += 8) {
            float w[8];
#pragma unroll
            for (int u = 0; u < 8; ++u) w[u] = wp[(size_t)(k0 + u) * OD_];
#pragma unroll
            for (int h = 0; h < 2; ++h) {
                int kb = k0 + h * 4;
                f32x4 bv[8];
#pragma unroll
                for (int g = 0; g < 8; ++g) bv[g] = *(const f32x4*)&basL[g][kb];
#pragma unroll
                for (int u = 0; u < 4; ++u) {
                    float wu = w[h * 4 + u];
#pragma unroll
                    for (int g = 0; g < 8; ++g) acc[g] += bv[g][u] * wu;   // k ascending
                }
            }
        }
        float fout[8] = {0.f, 0.f, 0.f, 0.f, 0.f, 0.f, 0.f, 0.f};
#pragma unroll
        for (int g = 0; g < 8; ++g) {
            if (g < rem) {
                int b = bidx[g];
                float cv = first ? 0.f : cur[b * D_ + d];
                float outv = cv + acc[g] + bov + biv;
                fout[g] = outv;
                cur[b * D_ + d] = outv;
                rx[b * D_ + d] = outv - x[b * D_ + d];
            }
        }

        // ---- fused gemm1 tail: zpart2[dt][b][h] for next layer's base ----
        if (!last) {
            __syncthreads();                 // k-loop readers of basL done
#pragma unroll
            for (int g = 0; g < 8; ++g) basL[g][t] = fout[g];   // now holds cur slice
            __syncthreads();
            const float* wbp = Wb + (size_t)(dt * 256) * H_ + t;
            float zacc[8] = {0.f, 0.f, 0.f, 0.f, 0.f, 0.f, 0.f, 0.f};
#pragma unroll 4
            for (int dd = 0; dd < 256; ++dd) {
                float w = wbp[(size_t)dd * H_];
#pragma unroll
                for (int g = 0; g < 8; ++g) zacc[g] += basL[g][dd] * w;   // d ascending
            }
#pragma unroll
            for (int g = 0; g < 8; ++g)
                if (g < rem)
                    zpart2[dt * (B_ * H_) + bidx[g] * H_ + t] = zacc[g];
        }
    }
}

// ---------------------------------------------------------------------------
extern "C" void kernel_launch(void* const* d_in, const int* in_sizes, int n_in,
                              void* d_out, int out_size, void* d_ws, size_t ws_size,
                              hipStream_t stream) {
    const float* x    = (const float*)d_in[0];  // [256][3072]
    const float* Wb   = (const float*)d_in[1];  // [3072][256]
    const float* bb   = (const float*)d_in[2];  // [256]
    const float* Wo   = (const float*)d_in[3];  // [4][256][98304]
    const float* bo   = (const float*)d_in[4];  // [4][98304]
    const float* bias = (const float*)d_in[5];  // [4][32][3072]

    float* out = (float*)d_out;
    float* enc = out;            // [256][4] (indices as float)
    float* cur = out + 1024;     // [256][3072] reconstruction

    float* ws = (float*)d_ws;
    float* zpart2  = ws;                          // 12*256*256 = 786432
    float* partial = ws + 786432;                 // 256*32*48  = 393216
    float* rx      = ws + 1179648;                // 256*3072   = 786432
    float* basef   = ws + 1966080;                // 256*256    = 65536
    unsigned char* base_ready = (unsigned char*)(ws + 2031616);  // 163840 B
    int* idxbuf    = (int*)(ws + 2072576);        // 256 ints
    int* dcnt      = (int*)(ws + 2072832);        // 1 int

    for (int i = 0; i < NL_; ++i) {
        const float* WoL   = Wo + (size_t)i * H_ * OD_;
        const float* boLp  = bo + (size_t)i * OD_;
        const float* biasL = bias + (size_t)i * OD_;
        const float* rp    = (i == 0) ? x : rx;
        float rsign        = (i == 0) ? -1.f : 1.f;
        e_kernel<<<256, 256, 0, stream>>>(zpart2, bb, base_ready, basef, dcnt, i == 0);
        g2_kernel<<<768, 512, 0, stream>>>(base_ready, WoL, biasL, boLp, rp, rsign, partial);
        d_kernel<<<dim3(32, 12), 256, 0, stream>>>(partial, enc, i, idxbuf, dcnt,
                                                   basef, WoL, boLp, biasL, x, Wb,
                                                   cur, rx, zpart2, i == 0, i == NL_ - 1);
    }
}

// Round 15
// 389.193 us; speedup vs baseline: 3.1405x; 1.2059x over previous
//
#include <hip/hip_runtime.h>
#include <hip/hip_bf16.h>

// Sizes
#define B_ 256
#define D_ 3072
#define H_ 256
#define OPT_ 32
#define OD_ 98304       // OPT_*D_
#define NL_ 4

typedef __attribute__((ext_vector_type(8))) short short8;
typedef __attribute__((ext_vector_type(4))) float f32x4;

__device__ __forceinline__ unsigned short f2bf(float f) {
    unsigned int u = __float_as_uint(f);
    unsigned int r = (u + 0x7FFFu + ((u >> 16) & 1u)) >> 16;
    return (unsigned short)r;
}

// ---------------------------------------------------------------------------
// E: base = relu(z + bb) -> bf16 image + f32 basef.
// Layer 0: z = bb (cur==0, so base = relu(bb) -- init kernel eliminated).
// Layers 1-3: z = bb + sum_{dt=0..11} zpart2[dt][m][k] (written by fused d).
__global__ __launch_bounds__(256) void e_kernel(const float* __restrict__ zpart2,
                                                const float* __restrict__ bb,
                                                unsigned char* __restrict__ base_ready,
                                                float* __restrict__ basef,
                                                int first) {
    int m = blockIdx.x, k = threadIdx.x;
    float z = bb[k];
    if (!first) {
#pragma unroll
        for (int dt = 0; dt < 12; ++dt) z += zpart2[dt * (B_ * H_) + m * H_ + k];
    }
    z = z > 0.f ? z : 0.f;
    *(unsigned short*)(base_ready + (k >> 5) * 20480 + m * 80 + (k & 31) * 2) = f2bf(z);
    basef[m * H_ + k] = z;
}

// ---------------------------------------------------------------------------
// G2 (R7 schedule): fused GEMM (256x98304, K=256, bf16 MFMA) +
// squared-loss partials. rp/rsign: layer 0 reads x with rsign=-1 (exact -x,
// replaces the init-written rx); layers 1-3 read rx with rsign=+1 (exact).
// Schedule: A staged by global_load_lds DMA (1 step ahead, L2-hot); W fp32
// loads in TWO register sets (X/Y) issued 2 steps ahead (HBM stream); raw
// s_barrier + counted "s_waitcnt vmcnt(8)" keeps the 8 in-flight W loads
// alive across each barrier. No sched_barrier (m141), unroll 2 only.
__global__ __launch_bounds__(512, 4) void g2_kernel(const unsigned char* __restrict__ base_ready,
                                                    const float* __restrict__ Wo,    // [256][98304] layer slice
                                                    const float* __restrict__ biasL, // [32*3072]
                                                    const float* __restrict__ boL,   // [98304]
                                                    const float* __restrict__ rp,    // rx or x
                                                    float rsign,
                                                    float* __restrict__ partial) {
    __shared__ __align__(16) unsigned char ldsA[2][20480];  // [m][32k bf16 + pad]
    __shared__ __align__(16) unsigned char ldsW[2][10240];  // [n][32k bf16 + pad]

    int t = threadIdx.x;
    int lane = t & 63, wv = t >> 6;
    int bx = blockIdx.x;
    int ncol0 = bx * 128;
    int o = bx / 24;                 // 24 blocks per option
    int dbase = (bx % 24) * 128;

    int wm = wv >> 1, wn = wv & 1;
    int lrow = lane & 15, lk = lane >> 4;
    int nW = t & 127, kq = t >> 7;   // W staging role: kq in 0..3

    f32x4 acc[4][4];
#pragma unroll
    for (int mi = 0; mi < 4; ++mi)
#pragma unroll
        for (int ni = 0; ni < 4; ++ni) acc[mi][ni] = 0.f;

    float wfX[8], wfY[8];

#define DMA_A(S, BUF) {                                                                  \
    const unsigned char* gA = base_ready + (S) * 20480;                                  \
    __builtin_amdgcn_global_load_lds(                                                    \
        (const __attribute__((address_space(1))) unsigned int*)(gA + t * 16),            \
        (__attribute__((address_space(3))) unsigned int*)(&ldsA[BUF][0] + wv * 1024),    \
        16, 0, 0);                                                                       \
    __builtin_amdgcn_global_load_lds(                                                    \
        (const __attribute__((address_space(1))) unsigned int*)(gA + 8192 + t * 16),     \
        (__attribute__((address_space(3))) unsigned int*)(&ldsA[BUF][0] + 8192 + wv * 1024), \
        16, 0, 0);                                                                       \
    if (wv < 4)                                                                          \
        __builtin_amdgcn_global_load_lds(                                                \
            (const __attribute__((address_space(1))) unsigned int*)(gA + 16384 + t * 16),\
            (__attribute__((address_space(3))) unsigned int*)(&ldsA[BUF][0] + 16384 + wv * 1024), \
            16, 0, 0); }

#define LOADW_(S, WF) {                                                                  \
    const float* gp0 = Wo + (size_t)((S) * 32 + kq * 4) * OD_ + ncol0 + nW;              \
    WF[0] = gp0[0]; WF[1] = gp0[OD_]; WF[2] = gp0[2 * OD_]; WF[3] = gp0[3 * OD_];        \
    const float* gp1 = gp0 + (size_t)16 * OD_;                                           \
    WF[4] = gp1[0]; WF[5] = gp1[OD_]; WF[6] = gp1[2 * OD_]; WF[7] = gp1[3 * OD_]; }

#define WRITEW_(BUF, WF) {                                                               \
    uint2 pk0, pk1;                                                                      \
    pk0.x = (unsigned)f2bf(WF[0]) | ((unsigned)f2bf(WF[1]) << 16);                       \
    pk0.y = (unsigned)f2bf(WF[2]) | ((unsigned)f2bf(WF[3]) << 16);                       \
    *(uint2*)(ldsW[BUF] + nW * 80 + kq * 8) = pk0;                                       \
    pk1.x = (unsigned)f2bf(WF[4]) | ((unsigned)f2bf(WF[5]) << 16);                       \
    pk1.y = (unsigned)f2bf(WF[6]) | ((unsigned)f2bf(WF[7]) << 16);                       \
    *(uint2*)(ldsW[BUF] + nW * 80 + 32 + kq * 8) = pk1; }

    DMA_A(0, 0);
    LOADW_(0, wfX);
    LOADW_(1, wfY);
    WRITEW_(0, wfX);
    asm volatile("s_waitcnt lgkmcnt(0)" ::: "memory");
    __builtin_amdgcn_s_barrier();

#pragma unroll 2
    for (int s = 0; s < 8; ++s) {
        int cur = s & 1;
        if (s < 7) DMA_A(s + 1, cur ^ 1);
        if (s < 6) {
            if ((s & 1) == 0) { LOADW_(s + 2, wfX); }
            else              { LOADW_(s + 2, wfY); }
        }
        short8 bfr[4];
#pragma unroll
        for (int ni = 0; ni < 4; ++ni) {
            int nn = wn * 64 + ni * 16 + lrow;
            bfr[ni] = *(const short8*)(ldsW[cur] + nn * 80 + lk * 16);
        }
#pragma unroll
        for (int mi = 0; mi < 4; ++mi) {
            int row = wm * 64 + mi * 16 + lrow;
            short8 af = *(const short8*)(ldsA[cur] + row * 80 + lk * 16);
#pragma unroll
            for (int ni = 0; ni < 4; ++ni)
                acc[mi][ni] = __builtin_amdgcn_mfma_f32_16x16x32_bf16(af, bfr[ni], acc[mi][ni], 0, 0, 0);
        }
        if (s < 7) {
            if ((s & 1) == 0) { WRITEW_(cur ^ 1, wfY); }
            else              { WRITEW_(cur ^ 1, wfX); }
            if (s < 6) asm volatile("s_waitcnt vmcnt(8) lgkmcnt(0)" ::: "memory");  // drain A(s+1); keep W(s+2)
            else       asm volatile("s_waitcnt vmcnt(0) lgkmcnt(0)" ::: "memory");  // last: drain A(7)
            __builtin_amdgcn_s_barrier();
        }
    }

#undef DMA_A
#undef LOADW_
#undef WRITEW_

    // epilogue: loss partials
    float q[4];
#pragma unroll
    for (int ni = 0; ni < 4; ++ni) {
        int dcol = dbase + wn * 64 + ni * 16 + lrow;
        q[ni] = biasL[o * D_ + dcol] + boL[o * D_ + dcol];
    }
    float ssum[4][4];
#pragma unroll
    for (int mi = 0; mi < 4; ++mi)
#pragma unroll
        for (int r = 0; r < 4; ++r) ssum[mi][r] = 0.f;

#pragma unroll
    for (int mi = 0; mi < 4; ++mi) {
#pragma unroll
        for (int ni = 0; ni < 4; ++ni) {
            int dcol = dbase + wn * 64 + ni * 16 + lrow;
#pragma unroll
            for (int r = 0; r < 4; ++r) {
                int rowm = wm * 64 + mi * 16 + lk * 4 + r;
                float tv = acc[mi][ni][r] + rsign * rp[rowm * D_ + dcol] + q[ni];
                ssum[mi][r] += tv * tv;
            }
        }
    }
#pragma unroll
    for (int mi = 0; mi < 4; ++mi)
#pragma unroll
        for (int r = 0; r < 4; ++r) {
            float v = ssum[mi][r];
            v += __shfl_xor(v, 1);
            v += __shfl_xor(v, 2);
            v += __shfl_xor(v, 4);
            v += __shfl_xor(v, 8);
            if (lrow == 0) {
                int rowm = wm * 64 + mi * 16 + lk * 4 + r;
                partial[(rowm * OPT_ + o) * 48 + (bx % 24) * 2 + wn] = v;
            }
        }
}

// ---------------------------------------------------------------------------
// C: per-b argmin over 32 options (tie-break lowest index = jnp.argmin).
__global__ __launch_bounds__(256) void c_kernel(const float* __restrict__ partial,
                                                int* __restrict__ idxbuf,
                                                float* __restrict__ enc, int layer) {
    __shared__ float ls[32];
    int b = blockIdx.x, t = threadIdx.x;
    int oo = t >> 3, j8 = t & 7;
    const float* pp = partial + (b * OPT_ + oo) * 48;
    float v = 0.f;
#pragma unroll
    for (int j = 0; j < 6; ++j) v += pp[j8 + 8 * j];
    v += __shfl_xor(v, 1);
    v += __shfl_xor(v, 2);
    v += __shfl_xor(v, 4);
    if (j8 == 0) ls[oo] = v;
    __syncthreads();
    if (t < 32) {
        float mv = ls[t];
        int mi = t;
#pragma unroll
        for (int m = 16; m >= 1; m >>= 1) {
            float ov = __shfl_xor(mv, m);
            int oi = __shfl_xor(mi, m);
            if (ov < mv || (ov == mv && oi < mi)) { mv = ov; mi = oi; }
        }
        if (t == 0) {
            idxbuf[b] = mi;
            enc[b * NL_ + layer] = (float)mi;
        }
    }
}

// ---------------------------------------------------------------------------
// D: bucketed recompute (deterministic rank-scan, no atomics) + FUSED
// next-layer gemm1 tail. grid (32 x 12), 256 threads. After writing cur/rx
// for its (chunk, d-slice), the block re-stages its cur values in LDS
// (reusing basL) and computes zpart2[dt][b][h] = sum_{d in slice} cur*Wb --
// replaces the standalone gemm1 launch. Skipped on the last layer.
// Layer 0: cv = 0 (cur was identically 0 -> init kernel eliminated).
__global__ __launch_bounds__(256) void d_kernel(const int* __restrict__ idxbuf,
                                                const float* __restrict__ basef,
                                                const float* __restrict__ Wo,
                                                const float* __restrict__ boL,
                                                const float* __restrict__ biasL,
                                                const float* __restrict__ x,
                                                const float* __restrict__ Wb,
                                                float* __restrict__ cur,
                                                float* __restrict__ rx,
                                                float* __restrict__ zpart2,
                                                int first, int last) {
    __shared__ int sidx[256];
    __shared__ int scnt[32];
    __shared__ int snch[32];
    __shared__ int chunk_b[8];
    __shared__ float basL[8][256];
    int t = threadIdx.x;
    int dt = blockIdx.y;

    sidx[t] = idxbuf[t];
    __syncthreads();
    if (t < 32) {
        int c = 0;
        for (int b = 0; b < 256; ++b) c += (sidx[b] == t);
        scnt[t] = c;
        snch[t] = (c + 7) >> 3;
    }
    __syncthreads();
    int myo = sidx[t];
    int myrank = 0;
    for (int b = 0; b < t; ++b) myrank += (sidx[b] == myo);

    for (int j = blockIdx.x; ; j += 32) {
        int o = -1, ch = 0, pre = 0;
        for (int oo = 0; oo < 32; ++oo) {
            int n = snch[oo];
            if (j < pre + n) { o = oo; ch = j - pre; break; }
            pre += n;
        }
        if (o < 0) break;
        int cnt = scnt[o];
        int c0 = ch * 8;
        int rem = cnt - c0;
        if (rem > 8) rem = 8;

        __syncthreads();   // previous item's basL readers done before reuse
        if (myo == o && myrank >= c0 && myrank < c0 + 8) chunk_b[myrank - c0] = t;
        __syncthreads();

        int bidx[8];
#pragma unroll
        for (int g = 0; g < 8; ++g) bidx[g] = chunk_b[(g < rem) ? g : (rem - 1)];
#pragma unroll
        for (int g = 0; g < 8; ++g) basL[g][t] = basef[bidx[g] * H_ + t];
        __syncthreads();

        int d = dt * 256 + t;
        const float* wp = Wo + (size_t)o * D_ + d;
        size_t nn = (size_t)o * D_ + d;
        float bov = boL[nn];
        float biv = biasL[nn];

        float acc[8] = {0.f, 0.f, 0.f, 0.f, 0.f, 0.f, 0.f, 0.f};
        for (int k0 = 0; k0 < 256; k0 += 8) {
            float w[8];
#pragma unroll
            for (int u = 0; u < 8; ++u) w[u] = wp[(size_t)(k0 + u) * OD_];
#pragma unroll
            for (int h = 0; h < 2; ++h) {
                int kb = k0 + h * 4;
                f32x4 bv[8];
#pragma unroll
                for (int g = 0; g < 8; ++g) bv[g] = *(const f32x4*)&basL[g][kb];
#pragma unroll
                for (int u = 0; u < 4; ++u) {
                    float wu = w[h * 4 + u];
#pragma unroll
                    for (int g = 0; g < 8; ++g) acc[g] += bv[g][u] * wu;   // k ascending
                }
            }
        }
        float fout[8] = {0.f, 0.f, 0.f, 0.f, 0.f, 0.f, 0.f, 0.f};
#pragma unroll
        for (int g = 0; g < 8; ++g) {
            if (g < rem) {
                int b = bidx[g];
                float cv = first ? 0.f : cur[b * D_ + d];
                float outv = cv + acc[g] + bov + biv;
                fout[g] = outv;
                cur[b * D_ + d] = outv;
                rx[b * D_ + d] = outv - x[b * D_ + d];
            }
        }

        // ---- fused gemm1 tail: zpart2[dt][b][h] for next layer's base ----
        if (!last) {
            __syncthreads();                 // k-loop readers of basL done
#pragma unroll
            for (int g = 0; g < 8; ++g) basL[g][t] = fout[g];   // now holds cur slice
            __syncthreads();
            const float* wbp = Wb + (size_t)(dt * 256) * H_ + t;
            float zacc[8] = {0.f, 0.f, 0.f, 0.f, 0.f, 0.f, 0.f, 0.f};
#pragma unroll 4
            for (int dd = 0; dd < 256; ++dd) {
                float w = wbp[(size_t)dd * H_];
#pragma unroll
                for (int g = 0; g < 8; ++g) zacc[g] += basL[g][dd] * w;   // d ascending
            }
#pragma unroll
            for (int g = 0; g < 8; ++g)
                if (g < rem)
                    zpart2[dt * (B_ * H_) + bidx[g] * H_ + t] = zacc[g];
        }
    }
}

// ---------------------------------------------------------------------------
extern "C" void kernel_launch(void* const* d_in, const int* in_sizes, int n_in,
                              void* d_out, int out_size, void* d_ws, size_t ws_size,
                              hipStream_t stream) {
    const float* x    = (const float*)d_in[0];  // [256][3072]
    const float* Wb   = (const float*)d_in[1];  // [3072][256]
    const float* bb   = (const float*)d_in[2];  // [256]
    const float* Wo   = (const float*)d_in[3];  // [4][256][98304]
    const float* bo   = (const float*)d_in[4];  // [4][98304]
    const float* bias = (const float*)d_in[5];  // [4][32][3072]

    float* out = (float*)d_out;
    float* enc = out;            // [256][4] (indices as float)
    float* cur = out + 1024;     // [256][3072] reconstruction

    float* ws = (float*)d_ws;
    float* zpart2  = ws;                          // 12*256*256 = 786432
    float* partial = ws + 786432;                 // 256*32*48  = 393216
    float* rx      = ws + 1179648;                // 256*3072   = 786432
    float* basef   = ws + 1966080;                // 256*256    = 65536
    unsigned char* base_ready = (unsigned char*)(ws + 2031616);  // 163840 B
    int* idxbuf    = (int*)(ws + 2072576);        // 256 ints

    for (int i = 0; i < NL_; ++i) {
        const float* WoL   = Wo + (size_t)i * H_ * OD_;
        const float* boLp  = bo + (size_t)i * OD_;
        const float* biasL = bias + (size_t)i * OD_;
        const float* rp    = (i == 0) ? x : rx;
        float rsign        = (i == 0) ? -1.f : 1.f;
        e_kernel<<<256, 256, 0, stream>>>(zpart2, bb, base_ready, basef, i == 0);
        g2_kernel<<<768, 512, 0, stream>>>(base_ready, WoL, biasL, boLp, rp, rsign, partial);
        c_kernel<<<256, 256, 0, stream>>>(partial, idxbuf, enc, i);
        d_kernel<<<dim3(32, 12), 256, 0, stream>>>(idxbuf, basef, WoL, boLp, biasL, x, Wb,
                                                   cur, rx, zpart2, i == 0, i == NL_ - 1);
    }
}